// Round 1
// baseline (337.121 us; speedup 1.0000x reference)
//
#include <hip/hip_runtime.h>
#include <hip/hip_bf16.h>

// Problem constants (fixed by the reference)
#define TT 2048
#define BB 4
#define CC 512
#define HH 16
#define KK 31
#define PP 15
#define RR 32           // CC/HH
#define MM (TT*BB)      // 8192 rows
#define HK (HH*KK)      // 496

// ---------------------------------------------------------------------------
// GEMM NT: C[m,n] = sum_k A[m,k] * B[n,k] (+ bias[n])
// A: [M,Kc] row-major, B: [N,Kc] row-major (i.e. we multiply by B^T).
// 64x64 output tile per block, 256 threads, 4x4 micro-tile per thread, BK=16.
// M and Kc are assumed multiples of 64/16; N may be ragged (496).
// ---------------------------------------------------------------------------
#define BM 64
#define BN 64
#define BK 16

__global__ __launch_bounds__(256) void gemm_nt(const float* __restrict__ A,
                                               const float* __restrict__ B,
                                               const float* __restrict__ bias,
                                               float* __restrict__ C,
                                               int M, int N, int Kc) {
    __shared__ float As[BK][BM + 1];
    __shared__ float Bs[BK][BN + 1];

    const int tid = threadIdx.x;
    const int bm  = blockIdx.x * BM;
    const int bn  = blockIdx.y * BN;
    const int tx  = tid & 15;    // 0..15 -> n direction
    const int ty  = tid >> 4;    // 0..15 -> m direction

    float acc[4][4] = {};

    for (int k0 = 0; k0 < Kc; k0 += BK) {
        // cooperative load: 64 rows x 16 cols, one float4 per thread per matrix
        const int r  = tid >> 2;         // 0..63
        const int c4 = (tid & 3) * 4;    // 0,4,8,12

        const float4 a = *(const float4*)&A[(size_t)(bm + r) * Kc + k0 + c4];
        As[c4 + 0][r] = a.x; As[c4 + 1][r] = a.y;
        As[c4 + 2][r] = a.z; As[c4 + 3][r] = a.w;

        float4 bv4 = make_float4(0.f, 0.f, 0.f, 0.f);
        if (bn + r < N)
            bv4 = *(const float4*)&B[(size_t)(bn + r) * Kc + k0 + c4];
        Bs[c4 + 0][r] = bv4.x; Bs[c4 + 1][r] = bv4.y;
        Bs[c4 + 2][r] = bv4.z; Bs[c4 + 3][r] = bv4.w;

        __syncthreads();

        #pragma unroll
        for (int kk = 0; kk < BK; ++kk) {
            float av[4], bv[4];
            #pragma unroll
            for (int i = 0; i < 4; ++i) av[i] = As[kk][ty * 4 + i];
            #pragma unroll
            for (int j = 0; j < 4; ++j) bv[j] = Bs[kk][tx * 4 + j];
            #pragma unroll
            for (int i = 0; i < 4; ++i)
                #pragma unroll
                for (int j = 0; j < 4; ++j)
                    acc[i][j] += av[i] * bv[j];
        }
        __syncthreads();
    }

    #pragma unroll
    for (int i = 0; i < 4; ++i) {
        const int m = bm + ty * 4 + i;
        #pragma unroll
        for (int j = 0; j < 4; ++j) {
            const int n = bn + tx * 4 + j;
            if (n < N)
                C[(size_t)m * N + n] = acc[i][j] + (bias ? bias[n] : 0.f);
        }
    }
}

// ---------------------------------------------------------------------------
// Softmax over K=31 per (m, head). w layout [M][H*K]; row m head h occupies
// w[m*496 + h*31 .. +31], which flattened over i = m*16+h is contiguous i*31.
// ---------------------------------------------------------------------------
__global__ __launch_bounds__(256) void softmax_k31(float* __restrict__ w, int rows) {
    const int i = blockIdx.x * blockDim.x + threadIdx.x;
    if (i >= rows) return;
    float* p = w + (size_t)i * KK;
    float mx = p[0];
    #pragma unroll
    for (int k = 1; k < KK; ++k) mx = fmaxf(mx, p[k]);
    float e[KK];
    float s = 0.f;
    #pragma unroll
    for (int k = 0; k < KK; ++k) { e[k] = __expf(p[k] - mx); s += e[k]; }
    const float inv = 1.f / s;
    #pragma unroll
    for (int k = 0; k < KK; ++k) p[k] = e[k] * inv;
}

// ---------------------------------------------------------------------------
// Dynamic conv: out[t,b,c] = sum_k h[t-P+k, b, c] * w[(t*B+b), head(c)*K + k]
// One thread per output element (m, c). Consecutive threads -> consecutive c
// -> coalesced h loads; w loads broadcast across the 32 lanes of a head.
// ---------------------------------------------------------------------------
__global__ __launch_bounds__(256) void dynconv(const float* __restrict__ h,
                                               const float* __restrict__ w,
                                               float* __restrict__ o) {
    const int idx = blockIdx.x * blockDim.x + threadIdx.x;   // over M*C
    const int c = idx & (CC - 1);
    const int m = idx >> 9;              // CC=512 -> >>9
    const int t = m >> 2;                // BB=4
    const int b = m & 3;
    const int hd = c >> 5;               // RR=32
    const float* wp = w + (size_t)m * HK + hd * KK;
    float acc = 0.f;
    #pragma unroll
    for (int k = 0; k < KK; ++k) {
        const int tt = t - PP + k;
        if (tt >= 0 && tt < TT)
            acc += h[(size_t)(tt * BB + b) * CC + c] * wp[k];
    }
    o[idx] = acc;
}

extern "C" void kernel_launch(void* const* d_in, const int* in_sizes, int n_in,
                              void* d_out, int out_size, void* d_ws, size_t ws_size,
                              hipStream_t stream) {
    const float* x  = (const float*)d_in[0];
    const float* W1 = (const float*)d_in[1];
    const float* b1 = (const float*)d_in[2];
    const float* Wl = (const float*)d_in[3];
    const float* W2 = (const float*)d_in[4];
    const float* b2 = (const float*)d_in[5];
    float* out = (float*)d_out;

    // workspace layout (floats): h[M*C], w[M*HK], cv[M*C]  -> ~49.8 MB
    float* h  = (float*)d_ws;
    float* w  = h + (size_t)MM * CC;
    float* cv = w + (size_t)MM * HK;

    // 1) h = x @ W1^T + b1
    gemm_nt<<<dim3(MM / BM, CC / BN), 256, 0, stream>>>(x, W1, b1, h, MM, CC, CC);
    // 2) w = h @ Wl^T
    gemm_nt<<<dim3(MM / BM, (HK + BN - 1) / BN), 256, 0, stream>>>(h, Wl, nullptr, w, MM, HK, CC);
    // 3) softmax over K per (m, head)
    softmax_k31<<<(MM * HH + 255) / 256, 256, 0, stream>>>(w, MM * HH);
    // 4) dynamic conv
    dynconv<<<(MM * CC) / 256, 256, 0, stream>>>(h, w, cv);
    // 5) out = cv @ W2^T + b2
    gemm_nt<<<dim3(MM / BM, CC / BN), 256, 0, stream>>>(cv, W2, b2, out, MM, CC, CC);
}

// Round 2
// 106.275 us; speedup vs baseline: 3.1722x; 3.1722x over previous
//
#include <hip/hip_runtime.h>
#include <hip/hip_bf16.h>

// Problem constants
#define TT 2048
#define BB 4
#define CC 512
#define HH 16
#define KK 31
#define PP 15
#define MM (TT*BB)      // 8192 rows
#define NPAD 512        // HK=496 padded to 512 (pad rows of Wl are zero)

typedef __bf16 bf16x8 __attribute__((ext_vector_type(8)));
typedef float f32x4 __attribute__((ext_vector_type(4)));
typedef unsigned short ushort8 __attribute__((ext_vector_type(8)));
typedef unsigned short ushort4v __attribute__((ext_vector_type(4)));

__device__ __forceinline__ float bf2f(unsigned short u) {
    return __uint_as_float(((unsigned int)u) << 16);
}
__device__ __forceinline__ unsigned short f2bf(float f) {
    unsigned int x = __float_as_uint(f);
    x += 0x7fffu + ((x >> 16) & 1u);
    return (unsigned short)(x >> 16);
}

// ---------------------------------------------------------------------------
// cast fp32 -> bf16, 4 elems/thread; zero-fills [n_src, n_dst) (Wl row pad)
// ---------------------------------------------------------------------------
__global__ __launch_bounds__(256) void cast_f32_bf16(const float* __restrict__ src,
                                                     unsigned short* __restrict__ dst,
                                                     int n_src, int n_dst) {
    const int i = (blockIdx.x * 256 + threadIdx.x) * 4;
    if (i >= n_dst) return;
    ushort4v o = {0, 0, 0, 0};
    if (i < n_src) {
        const float4 v = *(const float4*)&src[i];
        o[0] = f2bf(v.x); o[1] = f2bf(v.y); o[2] = f2bf(v.z); o[3] = f2bf(v.w);
    }
    *(ushort4v*)&dst[i] = o;
}

// ---------------------------------------------------------------------------
// bf16 MFMA GEMM-NT: C[m,n] = sum_k A[m,k]*B[n,k] (+bias[n])
// 128x64 tile, BK=32, 256 thr (4 waves 2x2, each 64x32 out).
// global_load_lds width=16 with linear LDS dest + pre-swizzled global source;
// ds_read uses the same swizzle (slot ^= (row>>1)&3) -> ~conflict-free b128.
// M%128==0, N%64==0, K%32==0 assumed (we pad Wl to 512 rows).
// ---------------------------------------------------------------------------
#define GBM 128
#define GBN 64
#define GBK 32

template<bool OUT_BF16>
__global__ __launch_bounds__(256, 2) void gemm_nt_mfma(const unsigned short* __restrict__ A,
                                                       const unsigned short* __restrict__ B,
                                                       const float* __restrict__ bias,
                                                       void* __restrict__ Cout,
                                                       int M, int N, int Kc) {
    __shared__ short As[GBM * GBK];   // 8 KB
    __shared__ short Bs[GBN * GBK];   // 4 KB

    const int tid = threadIdx.x;
    const int l   = tid & 63;
    const int wv  = tid >> 6;      // wave 0..3
    const int wr  = wv >> 1;       // wave row (0..1) -> 64 rows each
    const int wc  = wv & 1;        // wave col (0..1) -> 32 cols each
    const int bm  = blockIdx.x * GBM;
    const int bn  = blockIdx.y * GBN;

    // Staging: linear LDS [row][32] bf16; thread idx -> (row=idx>>2, slot=idx&3).
    // Source column pre-swizzled: slot' = slot ^ ((row>>1)&3)   (rule #21)
    const int ia0 = tid, ia1 = tid + 256, ib = tid;
    const unsigned short* gA0 = A + (size_t)(bm + (ia0 >> 2)) * Kc + (((ia0 & 3) ^ ((ia0 >> 3) & 3)) * 8);
    const unsigned short* gA1 = A + (size_t)(bm + (ia1 >> 2)) * Kc + (((ia1 & 3) ^ ((ia1 >> 3) & 3)) * 8);
    const unsigned short* gB  = B + (size_t)(bn + (ib  >> 2)) * Kc + (((ib  & 3) ^ ((ib  >> 3) & 3)) * 8);

    short* ldsA0 = As + wv * 512;          // wave-uniform dests
    short* ldsA1 = As + 2048 + wv * 512;
    short* ldsB  = Bs + wv * 512;

    f32x4 acc[4][2] = {};

    const int lr = l & 15;     // fragment row-within-16
    const int ls = l >> 4;     // k-slot 0..3 (8 bf16 each)
    int offA[4], offB[2];
    #pragma unroll
    for (int mi = 0; mi < 4; ++mi) {
        const int r = wr * 64 + mi * 16 + lr;
        offA[mi] = r * 32 + ((ls ^ ((r >> 1) & 3)) * 8);
    }
    #pragma unroll
    for (int ni = 0; ni < 2; ++ni) {
        const int r = wc * 32 + ni * 16 + lr;
        offB[ni] = r * 32 + ((ls ^ ((r >> 1) & 3)) * 8);
    }

    for (int k0 = 0; k0 < Kc; k0 += GBK) {
        __builtin_amdgcn_global_load_lds((const __attribute__((address_space(1))) void*)(gA0 + k0),
                                         (__attribute__((address_space(3))) void*)ldsA0, 16, 0, 0);
        __builtin_amdgcn_global_load_lds((const __attribute__((address_space(1))) void*)(gA1 + k0),
                                         (__attribute__((address_space(3))) void*)ldsA1, 16, 0, 0);
        __builtin_amdgcn_global_load_lds((const __attribute__((address_space(1))) void*)(gB + k0),
                                         (__attribute__((address_space(3))) void*)ldsB, 16, 0, 0);
        __syncthreads();   // compiler drains vmcnt before s_barrier

        bf16x8 af[4], bfv[2];
        #pragma unroll
        for (int mi = 0; mi < 4; ++mi) af[mi] = *(const bf16x8*)&As[offA[mi]];
        #pragma unroll
        for (int ni = 0; ni < 2; ++ni) bfv[ni] = *(const bf16x8*)&Bs[offB[ni]];

        #pragma unroll
        for (int mi = 0; mi < 4; ++mi)
            #pragma unroll
            for (int ni = 0; ni < 2; ++ni)
                acc[mi][ni] = __builtin_amdgcn_mfma_f32_16x16x32_bf16(af[mi], bfv[ni], acc[mi][ni], 0, 0, 0);
        __syncthreads();
    }

    // C/D layout (m89, HW-verified): col = lane&15, row = (lane>>4)*4 + j
    #pragma unroll
    for (int mi = 0; mi < 4; ++mi) {
        const int row0 = bm + wr * 64 + mi * 16 + ls * 4;
        #pragma unroll
        for (int ni = 0; ni < 2; ++ni) {
            const int col = bn + wc * 32 + ni * 16 + lr;
            const float bv = bias ? bias[col] : 0.0f;
            #pragma unroll
            for (int j = 0; j < 4; ++j) {
                const float v = acc[mi][ni][j] + bv;
                if (OUT_BF16)
                    ((unsigned short*)Cout)[(size_t)(row0 + j) * N + col] = f2bf(v);
                else
                    ((float*)Cout)[(size_t)(row0 + j) * N + col] = v;
            }
        }
    }
}

// ---------------------------------------------------------------------------
// Softmax over K=31 per (m, head); w layout [M][NPAD] fp32, head h at col h*31
// ---------------------------------------------------------------------------
__global__ __launch_bounds__(256) void softmax_k31(float* __restrict__ w) {
    const int i = blockIdx.x * 256 + threadIdx.x;       // over MM*HH
    float* p = w + (size_t)(i >> 4) * NPAD + (i & 15) * KK;
    float mx = p[0];
    #pragma unroll
    for (int k = 1; k < KK; ++k) mx = fmaxf(mx, p[k]);
    float e[KK];
    float s = 0.f;
    #pragma unroll
    for (int k = 0; k < KK; ++k) { e[k] = __expf(p[k] - mx); s += e[k]; }
    const float inv = 1.f / s;
    #pragma unroll
    for (int k = 0; k < KK; ++k) p[k] = e[k] * inv;
}

// ---------------------------------------------------------------------------
// Dynamic conv: 8 contiguous channels per thread (16B bf16 loads, coalesced).
// out[t,b,c0..c0+7] = sum_k h[t-P+k,b,c0..] * w[m, head*31+k]; writes bf16.
// ---------------------------------------------------------------------------
__global__ __launch_bounds__(256) void dynconv(const unsigned short* __restrict__ hb,
                                               const float* __restrict__ w,
                                               unsigned short* __restrict__ cvb) {
    const int idx = blockIdx.x * 256 + threadIdx.x;     // over MM*CC/8
    const int c0 = (idx & 63) * 8;
    const int m  = idx >> 6;
    const int t = m >> 2, b = m & 3;
    const float* wp = w + (size_t)m * NPAD + (c0 >> 5) * KK;   // wave-uniform
    float acc[8] = {};
    #pragma unroll
    for (int k = 0; k < KK; ++k) {
        const int tt = t - PP + k;
        if (tt < 0 || tt >= TT) continue;
        const ushort8 hv = *(const ushort8*)&hb[(size_t)((tt * BB + b) * CC) + c0];
        const float wk = wp[k];
        #pragma unroll
        for (int j = 0; j < 8; ++j) acc[j] = fmaf(bf2f(hv[j]), wk, acc[j]);
    }
    ushort8 o;
    #pragma unroll
    for (int j = 0; j < 8; ++j) o[j] = f2bf(acc[j]);
    *(ushort8*)&cvb[(size_t)idx * 8] = o;
}

extern "C" void kernel_launch(void* const* d_in, const int* in_sizes, int n_in,
                              void* d_out, int out_size, void* d_ws, size_t ws_size,
                              hipStream_t stream) {
    const float* x  = (const float*)d_in[0];
    const float* W1 = (const float*)d_in[1];
    const float* b1 = (const float*)d_in[2];
    const float* Wl = (const float*)d_in[3];
    const float* W2 = (const float*)d_in[4];
    const float* b2 = (const float*)d_in[5];
    float* out = (float*)d_out;

    // workspace layout
    unsigned short* xb  = (unsigned short*)d_ws;             // 8 MB
    unsigned short* hb  = xb  + (size_t)MM * CC;             // 8 MB
    unsigned short* cvb = hb  + (size_t)MM * CC;             // 8 MB
    unsigned short* W1b = cvb + (size_t)MM * CC;             // 0.5 MB
    unsigned short* Wlb = W1b + (size_t)CC * CC;             // 0.5 MB (padded)
    unsigned short* W2b = Wlb + (size_t)NPAD * CC;           // 0.5 MB
    float*          wgt = (float*)(W2b + (size_t)CC * CC);   // 16 MB fp32

    const int nxc = MM * CC;           // 4194304
    const int nw  = CC * CC;           // 262144

    // input casts
    cast_f32_bf16<<<nxc / 1024, 256, 0, stream>>>(x,  xb,  nxc, nxc);
    cast_f32_bf16<<<nw  / 1024, 256, 0, stream>>>(W1, W1b, nw,  nw);
    cast_f32_bf16<<<nw  / 1024, 256, 0, stream>>>(Wl, Wlb, HH * KK * CC, NPAD * CC);  // zero-pad rows 496..511
    cast_f32_bf16<<<nw  / 1024, 256, 0, stream>>>(W2, W2b, nw,  nw);

    const dim3 ggrid(MM / GBM, CC / GBN);   // (64, 8)

    // 1) h = x @ W1^T + b1   (bf16 out)
    gemm_nt_mfma<true><<<ggrid, 256, 0, stream>>>(xb, W1b, b1, hb, MM, CC, CC);
    // 2) w = h @ Wl^T        (fp32 out, padded N)
    gemm_nt_mfma<false><<<ggrid, 256, 0, stream>>>(hb, Wlb, nullptr, wgt, MM, NPAD, CC);
    // 3) softmax over K per (m, head)
    softmax_k31<<<(MM * HH) / 256, 256, 0, stream>>>(wgt);
    // 4) dynamic conv        (bf16 out)
    dynconv<<<(MM * CC / 8) / 256, 256, 0, stream>>>(hb, wgt, cvb);
    // 5) out = cv @ W2^T + b2  (fp32 out)
    gemm_nt_mfma<false><<<ggrid, 256, 0, stream>>>(cvb, W2b, b2, out, MM, CC, CC);
}

// Round 3
// 70.216 us; speedup vs baseline: 4.8012x; 1.5135x over previous
//
#include <hip/hip_runtime.h>
#include <hip/hip_bf16.h>

// Problem constants
#define TT 2048
#define BB 4
#define CC 512
#define HH 16
#define KK 31
#define PP 15
#define MM (TT*BB)      // 8192 rows
#define NPAD 512        // HK=496 padded to 512 (pad rows of Wl are zero)

typedef __bf16 bf16x8 __attribute__((ext_vector_type(8)));
typedef float f32x4 __attribute__((ext_vector_type(4)));
typedef unsigned short ushort8 __attribute__((ext_vector_type(8)));
typedef unsigned short ushort4v __attribute__((ext_vector_type(4)));

__device__ __forceinline__ float bf2f(unsigned short u) {
    return __uint_as_float(((unsigned int)u) << 16);
}
__device__ __forceinline__ unsigned short f2bf(float f) {
    unsigned int x = __float_as_uint(f);
    x += 0x7fffu + ((x >> 16) & 1u);
    return (unsigned short)(x >> 16);
}

// ---------------------------------------------------------------------------
// cast fp32 -> bf16, 4 elems/thread; zero-fills [n_src, n_dst) (Wl row pad)
// ---------------------------------------------------------------------------
__global__ __launch_bounds__(256) void cast_f32_bf16(const float* __restrict__ src,
                                                     unsigned short* __restrict__ dst,
                                                     int n_src, int n_dst) {
    const int i = (blockIdx.x * 256 + threadIdx.x) * 4;
    if (i >= n_dst) return;
    ushort4v o = {0, 0, 0, 0};
    if (i < n_src) {
        const float4 v = *(const float4*)&src[i];
        o[0] = f2bf(v.x); o[1] = f2bf(v.y); o[2] = f2bf(v.z); o[3] = f2bf(v.w);
    }
    *(ushort4v*)&dst[i] = o;
}

// ---------------------------------------------------------------------------
// bf16 MFMA GEMM-NT: C[m,n] = sum_k A[m,k]*B[n,k] (+bias[n])
// 128x64 tile, BK=32, 256 thr (4 waves 2x2, each 64x32 out).
// global_load_lds width=16, linear LDS dest + pre-swizzled global source;
// ds_read uses the same swizzle (slot ^= (row>>1)&3).
// ---------------------------------------------------------------------------
#define GBM 128
#define GBN 64
#define GBK 32

template<bool OUT_BF16>
__global__ __launch_bounds__(256, 2) void gemm_nt_mfma(const unsigned short* __restrict__ A,
                                                       const unsigned short* __restrict__ B,
                                                       const float* __restrict__ bias,
                                                       void* __restrict__ Cout,
                                                       int M, int N, int Kc) {
    __shared__ short As[GBM * GBK];   // 8 KB
    __shared__ short Bs[GBN * GBK];   // 4 KB

    const int tid = threadIdx.x;
    const int l   = tid & 63;
    const int wv  = tid >> 6;      // wave 0..3
    const int wr  = wv >> 1;       // wave row (0..1) -> 64 rows each
    const int wc  = wv & 1;        // wave col (0..1) -> 32 cols each
    const int bm  = blockIdx.x * GBM;
    const int bn  = blockIdx.y * GBN;

    const int ia0 = tid, ia1 = tid + 256, ib = tid;
    const unsigned short* gA0 = A + (size_t)(bm + (ia0 >> 2)) * Kc + (((ia0 & 3) ^ ((ia0 >> 3) & 3)) * 8);
    const unsigned short* gA1 = A + (size_t)(bm + (ia1 >> 2)) * Kc + (((ia1 & 3) ^ ((ia1 >> 3) & 3)) * 8);
    const unsigned short* gB  = B + (size_t)(bn + (ib  >> 2)) * Kc + (((ib  & 3) ^ ((ib  >> 3) & 3)) * 8);

    short* ldsA0 = As + wv * 512;
    short* ldsA1 = As + 2048 + wv * 512;
    short* ldsB  = Bs + wv * 512;

    f32x4 acc[4][2] = {};

    const int lr = l & 15;     // fragment row-within-16
    const int ls = l >> 4;     // k-slot 0..3 (8 bf16 each)
    int offA[4], offB[2];
    #pragma unroll
    for (int mi = 0; mi < 4; ++mi) {
        const int r = wr * 64 + mi * 16 + lr;
        offA[mi] = r * 32 + ((ls ^ ((r >> 1) & 3)) * 8);
    }
    #pragma unroll
    for (int ni = 0; ni < 2; ++ni) {
        const int r = wc * 32 + ni * 16 + lr;
        offB[ni] = r * 32 + ((ls ^ ((r >> 1) & 3)) * 8);
    }

    for (int k0 = 0; k0 < Kc; k0 += GBK) {
        __builtin_amdgcn_global_load_lds((const __attribute__((address_space(1))) void*)(gA0 + k0),
                                         (__attribute__((address_space(3))) void*)ldsA0, 16, 0, 0);
        __builtin_amdgcn_global_load_lds((const __attribute__((address_space(1))) void*)(gA1 + k0),
                                         (__attribute__((address_space(3))) void*)ldsA1, 16, 0, 0);
        __builtin_amdgcn_global_load_lds((const __attribute__((address_space(1))) void*)(gB + k0),
                                         (__attribute__((address_space(3))) void*)ldsB, 16, 0, 0);
        __syncthreads();

        bf16x8 af[4], bfv[2];
        #pragma unroll
        for (int mi = 0; mi < 4; ++mi) af[mi] = *(const bf16x8*)&As[offA[mi]];
        #pragma unroll
        for (int ni = 0; ni < 2; ++ni) bfv[ni] = *(const bf16x8*)&Bs[offB[ni]];

        #pragma unroll
        for (int mi = 0; mi < 4; ++mi)
            #pragma unroll
            for (int ni = 0; ni < 2; ++ni)
                acc[mi][ni] = __builtin_amdgcn_mfma_f32_16x16x32_bf16(af[mi], bfv[ni], acc[mi][ni], 0, 0, 0);
        __syncthreads();
    }

    // C/D layout (m89): col = lane&15, row = (lane>>4)*4 + j
    #pragma unroll
    for (int mi = 0; mi < 4; ++mi) {
        const int row0 = bm + wr * 64 + mi * 16 + ls * 4;
        #pragma unroll
        for (int ni = 0; ni < 2; ++ni) {
            const int col = bn + wc * 32 + ni * 16 + lr;
            const float bv = bias ? bias[col] : 0.0f;
            #pragma unroll
            for (int j = 0; j < 4; ++j) {
                const float v = acc[mi][ni][j] + bv;
                if (OUT_BF16)
                    ((unsigned short*)Cout)[(size_t)(row0 + j) * N + col] = f2bf(v);
                else
                    ((float*)Cout)[(size_t)(row0 + j) * N + col] = v;
            }
        }
    }
}

// ---------------------------------------------------------------------------
// Fused softmax + dynamic conv. One block per t (all 4 b, all 512 c).
// Phase 1: 64 softmax rows (b,head) from raw logits -> LDS [64][32] fp32.
//          4 lanes per row, shfl_xor(width 4) reduce.
// Phase 2: thread = (b, c0=8ch): 31-tap conv, h from global (L2 via XCD
//          chunked swizzle), weights broadcast from LDS. bf16 out.
// ---------------------------------------------------------------------------
__global__ __launch_bounds__(256) void dynconv_fused(const unsigned short* __restrict__ hb,
                                                     const float* __restrict__ logits,
                                                     unsigned short* __restrict__ cvb) {
    __shared__ float w_s[64][32];   // 8 KB

    // chunked XCD swizzle: XCD x owns t in [x*256, (x+1)*256)  (2048 % 8 == 0)
    const int bid = blockIdx.x;
    const int t   = (bid & 7) * 256 + (bid >> 3);
    const int tid = threadIdx.x;

    // ---- Phase 1: softmax over K=31 for 64 rows, 4 lanes each ----
    {
        const int r = tid >> 2;          // row 0..63: b = r>>4, head = r&15
        const int q = tid & 3;           // lane-in-group
        const int b = r >> 4, hd = r & 15;
        const float* lp = logits + (size_t)(t * BB + b) * NPAD + hd * KK;
        float e[8];
        const int k0 = q * 8;
        const int kn = (q == 3) ? 7 : 8;
        float mx = -1e30f;
        #pragma unroll
        for (int j = 0; j < 8; ++j) {
            e[j] = (j < kn) ? lp[k0 + j] : -1e30f;
            mx = fmaxf(mx, e[j]);
        }
        mx = fmaxf(mx, __shfl_xor(mx, 1, 4));
        mx = fmaxf(mx, __shfl_xor(mx, 2, 4));
        float s = 0.f;
        #pragma unroll
        for (int j = 0; j < 8; ++j) {
            e[j] = (j < kn) ? __expf(e[j] - mx) : 0.f;
            s += e[j];
        }
        s += __shfl_xor(s, 1, 4);
        s += __shfl_xor(s, 2, 4);
        const float inv = 1.f / s;
        #pragma unroll
        for (int j = 0; j < 8; ++j)
            if (j < kn) w_s[r][k0 + j] = e[j] * inv;
    }
    __syncthreads();

    // ---- Phase 2: conv ----
    const int c0 = (tid & 63) * 8;       // channel group; wave = one b, 512 ch
    const int b  = tid >> 6;
    const int wrow = b * 16 + (c0 >> 5); // (b, head)
    float acc[8] = {};
    #pragma unroll
    for (int k = 0; k < KK; ++k) {
        const int tt = t - PP + k;
        if ((unsigned)tt >= TT) continue;
        const ushort8 hv = *(const ushort8*)&hb[(size_t)((tt * BB + b) * CC) + c0];
        const float wk = w_s[wrow][k];
        #pragma unroll
        for (int j = 0; j < 8; ++j) acc[j] = fmaf(bf2f(hv[j]), wk, acc[j]);
    }
    ushort8 o;
    #pragma unroll
    for (int j = 0; j < 8; ++j) o[j] = f2bf(acc[j]);
    *(ushort8*)&cvb[(size_t)((t * BB + b) * CC) + c0] = o;
}

extern "C" void kernel_launch(void* const* d_in, const int* in_sizes, int n_in,
                              void* d_out, int out_size, void* d_ws, size_t ws_size,
                              hipStream_t stream) {
    const float* x  = (const float*)d_in[0];
    const float* W1 = (const float*)d_in[1];
    const float* b1 = (const float*)d_in[2];
    const float* Wl = (const float*)d_in[3];
    const float* W2 = (const float*)d_in[4];
    const float* b2 = (const float*)d_in[5];
    float* out = (float*)d_out;

    // workspace layout
    unsigned short* xb  = (unsigned short*)d_ws;             // 8 MB
    unsigned short* hb  = xb  + (size_t)MM * CC;             // 8 MB
    unsigned short* cvb = hb  + (size_t)MM * CC;             // 8 MB
    unsigned short* W1b = cvb + (size_t)MM * CC;             // 0.5 MB
    unsigned short* Wlb = W1b + (size_t)CC * CC;             // 0.5 MB (padded)
    unsigned short* W2b = Wlb + (size_t)NPAD * CC;           // 0.5 MB
    float*          wgt = (float*)(W2b + (size_t)CC * CC);   // 16 MB fp32 logits

    const int nxc = MM * CC;           // 4194304
    const int nw  = CC * CC;           // 262144

    cast_f32_bf16<<<nxc / 1024, 256, 0, stream>>>(x,  xb,  nxc, nxc);
    cast_f32_bf16<<<nw  / 1024, 256, 0, stream>>>(W1, W1b, nw,  nw);
    cast_f32_bf16<<<nw  / 1024, 256, 0, stream>>>(Wl, Wlb, HH * KK * CC, NPAD * CC);
    cast_f32_bf16<<<nw  / 1024, 256, 0, stream>>>(W2, W2b, nw,  nw);

    const dim3 ggrid(MM / GBM, CC / GBN);   // (64, 8)

    // 1) h = x @ W1^T + b1   (bf16 out)
    gemm_nt_mfma<true><<<ggrid, 256, 0, stream>>>(xb, W1b, b1, hb, MM, CC, CC);
    // 2) logits = h @ Wl^T   (fp32 out, padded N)
    gemm_nt_mfma<false><<<ggrid, 256, 0, stream>>>(hb, Wlb, nullptr, wgt, MM, NPAD, CC);
    // 3+4) fused softmax + dynamic conv (bf16 out)
    dynconv_fused<<<TT, 256, 0, stream>>>(hb, wgt, cvb);
    // 5) out = cv @ W2^T + b2  (fp32 out)
    gemm_nt_mfma<false><<<ggrid, 256, 0, stream>>>(cvb, W2b, b2, out, MM, CC, CC);
}